// Round 13
// baseline (304.926 us; speedup 1.0000x reference)
//
#include <hip/hip_runtime.h>
#include <math.h>

#define N_NODES   100000
#define N_EDGES   1600000
#define D_FEAT    64
#define N_CH      64

#define SELU_SCALE 1.0507009873554805f
#define SELU_ALPHA 1.6732632423543772f

// ------------------------- scan config -------------------------
#define SCAN_TPB   256
#define SCAN_ELEMS 1024                                   // 4 per thread
#define SCAN_NB    ((N_NODES + SCAN_ELEMS - 1) / SCAN_ELEMS)   // 98

// ------------------------- gemm config -------------------------
#define G_ROWS_PER_WAVE 16
#define G_ROWS_PER_BLOCK (4 * G_ROWS_PER_WAVE)   // 64
#define NB_GEMM  ((N_NODES + G_ROWS_PER_BLOCK - 1) / G_ROWS_PER_BLOCK)  // 1563
#define NB_SCAT4 ((N_EDGES / 4 + 255) / 256)     // 1563 (4 edges per thread)
#define NB_SCAT8 ((N_EDGES / 8 + 255) / 256)     // 782  (8 edges per thread)

// ---- bf16 helpers (no type deps: raw ushort bits) ----
__device__ __forceinline__ unsigned short f2bf_rne(float x)
{
    unsigned b = __float_as_uint(x);
    unsigned r = (b + 0x7FFFu + ((b >> 16) & 1u)) >> 16;   // round-nearest-even
    return (unsigned short)r;
}
__device__ __forceinline__ float bf2f(unsigned short u)
{
    return __uint_as_float(((unsigned)u) << 16);
}

// ===========================================================================
// GEMM body: h_bf = bf16(features @ W + bias).  Lane = channel; W column in
// 64 VGPRs; feature row via wave-uniform scalar loads.
// ===========================================================================
__device__ __forceinline__ void gemm_body_bf16(
    int gb,
    const float* __restrict__ feat,
    const float* __restrict__ W,
    const float* __restrict__ bias,
    unsigned short* __restrict__ h_bf)
{
    int lane = threadIdx.x & 63;
    int wave = threadIdx.x >> 6;

    float Wc[D_FEAT];
    #pragma unroll
    for (int k = 0; k < D_FEAT; ++k) Wc[k] = W[k * N_CH + lane];
    float b = bias[lane];

    int row0 = (gb * 4 + wave) * G_ROWS_PER_WAVE;
    for (int r = 0; r < G_ROWS_PER_WAVE; ++r) {
        int row = row0 + r;
        if (row >= N_NODES) return;
        int row_u = __builtin_amdgcn_readfirstlane(row);
        const float* frow = feat + (size_t)row_u * D_FEAT;
        float a0 = b, a1 = 0.f, a2 = 0.f, a3 = 0.f;
        #pragma unroll
        for (int k = 0; k < D_FEAT; k += 4) {
            a0 = fmaf(frow[k + 0], Wc[k + 0], a0);
            a1 = fmaf(frow[k + 1], Wc[k + 1], a1);
            a2 = fmaf(frow[k + 2], Wc[k + 2], a2);
            a3 = fmaf(frow[k + 3], Wc[k + 3], a3);
        }
        h_bf[row * N_CH + lane] = f2bf_rne((a0 + a1) + (a2 + a3));
    }
}

// ===========================================================================
// Fused head: degree histogram + per-edge rank (atomic return)  ||  GEMM.
// 8 edges/thread -> 8 independent atomic-returns in flight (2x the MLP of
// the measured R12 version, which was latency-bound at VALUBusy 5.5%).
// ===========================================================================
__global__ __launch_bounds__(256) void zero_deg_kernel(int* __restrict__ deg)
{
    int i = blockIdx.x * 256 + threadIdx.x;
    if (i < N_NODES) deg[i] = 0;
}

__global__ __launch_bounds__(256) void degree_rank_gemm_kernel(
    const int* __restrict__ rows, int* __restrict__ deg, int* __restrict__ rank,
    const float* __restrict__ feat, const float* __restrict__ W,
    const float* __restrict__ bias, unsigned short* __restrict__ h_bf)
{
    if (blockIdx.x < NB_SCAT8) {
        int i = blockIdx.x * 256 + threadIdx.x;
        if (i < N_EDGES / 8) {
            const int4 ra = reinterpret_cast<const int4*>(rows)[2 * i + 0];
            const int4 rb = reinterpret_cast<const int4*>(rows)[2 * i + 1];
            int4 ka, kb;
            ka.x = atomicAdd(&deg[ra.x], 1);
            ka.y = atomicAdd(&deg[ra.y], 1);
            ka.z = atomicAdd(&deg[ra.z], 1);
            ka.w = atomicAdd(&deg[ra.w], 1);
            kb.x = atomicAdd(&deg[rb.x], 1);
            kb.y = atomicAdd(&deg[rb.y], 1);
            kb.z = atomicAdd(&deg[rb.z], 1);
            kb.w = atomicAdd(&deg[rb.w], 1);
            reinterpret_cast<int4*>(rank)[2 * i + 0] = ka;
            reinterpret_cast<int4*>(rank)[2 * i + 1] = kb;
        }
    } else {
        gemm_body_bf16(blockIdx.x - NB_SCAT8, feat, W, bias, h_bf);
    }
}

// ===========================================================================
// Exclusive scan of deg -> row_start (3 kernels)
// ===========================================================================
__global__ __launch_bounds__(SCAN_TPB) void scan1_kernel(
    const int* __restrict__ deg, int* __restrict__ row_start,
    int* __restrict__ partials)
{
    __shared__ int lds[SCAN_TPB];
    int t = threadIdx.x;
    int base = blockIdx.x * SCAN_ELEMS + t * 4;
    int v0 = (base + 0 < N_NODES) ? deg[base + 0] : 0;
    int v1 = (base + 1 < N_NODES) ? deg[base + 1] : 0;
    int v2 = (base + 2 < N_NODES) ? deg[base + 2] : 0;
    int v3 = (base + 3 < N_NODES) ? deg[base + 3] : 0;
    int s1 = v0, s2 = v0 + v1, s3 = v0 + v1 + v2, tot = v0 + v1 + v2 + v3;
    lds[t] = tot;
    __syncthreads();
    for (int off = 1; off < SCAN_TPB; off <<= 1) {
        int y = (t >= off) ? lds[t - off] : 0;
        __syncthreads();
        lds[t] += y;
        __syncthreads();
    }
    int texcl = (t > 0) ? lds[t - 1] : 0;
    if (t == SCAN_TPB - 1) partials[blockIdx.x] = lds[SCAN_TPB - 1];
    if (base + 0 < N_NODES) row_start[base + 0] = texcl;
    if (base + 1 < N_NODES) row_start[base + 1] = texcl + s1;
    if (base + 2 < N_NODES) row_start[base + 2] = texcl + s2;
    if (base + 3 < N_NODES) row_start[base + 3] = texcl + s3;
}

__global__ __launch_bounds__(128) void scan2_kernel(int* __restrict__ partials)
{
    __shared__ int lds[128];
    int t = threadIdx.x;
    lds[t] = (t < SCAN_NB) ? partials[t] : 0;
    __syncthreads();
    for (int off = 1; off < 128; off <<= 1) {
        int y = (t >= off) ? lds[t - off] : 0;
        __syncthreads();
        lds[t] += y;
        __syncthreads();
    }
    if (t < SCAN_NB) partials[t] = (t > 0) ? lds[t - 1] : 0;
}

__global__ __launch_bounds__(SCAN_TPB) void scan3_kernel(
    int* __restrict__ row_start, const int* __restrict__ partials)
{
    int t = threadIdx.x;
    int add = partials[blockIdx.x];
    int base = blockIdx.x * SCAN_ELEMS + t * 4;
    #pragma unroll
    for (int j = 0; j < 4; ++j) {
        int idx = base + j;
        if (idx < N_NODES) row_start[idx] += add;
    }
    if (blockIdx.x == 0 && t == 0) row_start[N_NODES] = N_EDGES;
}

// ===========================================================================
// Non-atomic CSR scatter of PACKED (col,val) 8B records (standalone).
// ===========================================================================
__global__ __launch_bounds__(256) void scatter_pack_kernel(
    const int* __restrict__ rows, const int* __restrict__ rank,
    const int* __restrict__ cols, const float* __restrict__ vals,
    const int* __restrict__ row_start, unsigned long long* __restrict__ pack64)
{
    int i = blockIdx.x * 256 + threadIdx.x;
    if (i < N_EDGES / 4) {
        const int4   r  = reinterpret_cast<const int4*>(rows)[i];
        const int4   rk = reinterpret_cast<const int4*>(rank)[i];
        const int4   c  = reinterpret_cast<const int4*>(cols)[i];
        const float4 v  = reinterpret_cast<const float4*>(vals)[i];
        unsigned long long p0 =
            ((unsigned long long)__float_as_uint(v.x) << 32) | (unsigned)c.x;
        unsigned long long p1 =
            ((unsigned long long)__float_as_uint(v.y) << 32) | (unsigned)c.y;
        unsigned long long p2 =
            ((unsigned long long)__float_as_uint(v.z) << 32) | (unsigned)c.z;
        unsigned long long p3 =
            ((unsigned long long)__float_as_uint(v.w) << 32) | (unsigned)c.w;
        __builtin_nontemporal_store(p0, &pack64[row_start[r.x] + rk.x]);
        __builtin_nontemporal_store(p1, &pack64[row_start[r.y] + rk.y]);
        __builtin_nontemporal_store(p2, &pack64[row_start[r.z] + rk.z]);
        __builtin_nontemporal_store(p3, &pack64[row_start[r.w] + rk.w]);
    }
}

// ===========================================================================
// Aggregate: TWO rows per wave, lane = channel, bf16 h gathers (128B/wave).
// 2-deep chain: pack[j] -> h_bf[col].  Fused skip+SeLU epilogue (fp32 acc).
// ===========================================================================
__global__ __launch_bounds__(256) void aggregate_pack_kernel(
    const int*   __restrict__ row_start,
    const uint2* __restrict__ pack,
    const unsigned short* __restrict__ h_bf,
    const float* __restrict__ skip,
    float*       __restrict__ out)
{
    int pair = blockIdx.x * 4 + (threadIdx.x >> 6);   // wave id = row pair
    int lane = threadIdx.x & 63;
    int r0 = pair * 2;
    if (r0 >= N_NODES) return;
    int r1 = r0 + 1;                                  // N_NODES even -> valid

    int s0 = row_start[r0], e0 = row_start[r0 + 1];
    int s1 = row_start[r1], e1 = row_start[r1 + 1];
    float skp = skip[lane];

    float a0 = 0.f, a1 = 0.f, a2 = 0.f, a3 = 0.f;   // row0 chains
    float b0 = 0.f, b1 = 0.f, b2 = 0.f, b3 = 0.f;   // row1 chains

    int j0 = s0, j1 = s1;
    while (j0 < e0 || j1 < e1) {
        int cnt0 = e0 - j0; cnt0 = cnt0 < 0 ? 0 : (cnt0 > 64 ? 64 : cnt0);
        int cnt1 = e1 - j1; cnt1 = cnt1 < 0 ? 0 : (cnt1 > 64 ? 64 : cnt1);
        uint2 p0 = make_uint2(0u, 0u), p1 = make_uint2(0u, 0u);
        if (lane < cnt0) p0 = pack[j0 + lane];        // coalesced 512B
        if (lane < cnt1) p1 = pack[j1 + lane];
        int pc = cnt0 > cnt1 ? cnt0 : cnt1;
        pc = (pc + 3) & ~3;
        for (int k = 0; k < pc; k += 4) {
            // v=0 padding (zero-init p) -> fma contributes 0 for dead slots
            int   c00 = __shfl((int)p0.x, k + 0, 64); float v00 = __shfl(__uint_as_float(p0.y), k + 0, 64);
            int   c10 = __shfl((int)p1.x, k + 0, 64); float v10 = __shfl(__uint_as_float(p1.y), k + 0, 64);
            int   c01 = __shfl((int)p0.x, k + 1, 64); float v01 = __shfl(__uint_as_float(p0.y), k + 1, 64);
            int   c11 = __shfl((int)p1.x, k + 1, 64); float v11 = __shfl(__uint_as_float(p1.y), k + 1, 64);
            int   c02 = __shfl((int)p0.x, k + 2, 64); float v02 = __shfl(__uint_as_float(p0.y), k + 2, 64);
            int   c12 = __shfl((int)p1.x, k + 2, 64); float v12 = __shfl(__uint_as_float(p1.y), k + 2, 64);
            int   c03 = __shfl((int)p0.x, k + 3, 64); float v03 = __shfl(__uint_as_float(p0.y), k + 3, 64);
            int   c13 = __shfl((int)p1.x, k + 3, 64); float v13 = __shfl(__uint_as_float(p1.y), k + 3, 64);
            float g00 = bf2f(h_bf[c00 * N_CH + lane]);
            float g10 = bf2f(h_bf[c10 * N_CH + lane]);
            float g01 = bf2f(h_bf[c01 * N_CH + lane]);
            float g11 = bf2f(h_bf[c11 * N_CH + lane]);
            float g02 = bf2f(h_bf[c02 * N_CH + lane]);
            float g12 = bf2f(h_bf[c12 * N_CH + lane]);
            float g03 = bf2f(h_bf[c03 * N_CH + lane]);
            float g13 = bf2f(h_bf[c13 * N_CH + lane]);
            a0 = fmaf(v00, g00, a0);
            b0 = fmaf(v10, g10, b0);
            a1 = fmaf(v01, g01, a1);
            b1 = fmaf(v11, g11, b1);
            a2 = fmaf(v02, g02, a2);
            b2 = fmaf(v12, g12, b2);
            a3 = fmaf(v03, g03, a3);
            b3 = fmaf(v13, g13, b3);
        }
        j0 += 64; j1 += 64;
    }
    float x0 = (a0 + a1) + (a2 + a3) + skp;
    float x1 = (b0 + b1) + (b2 + b3) + skp;
    float n0 = SELU_SCALE * SELU_ALPHA * expm1f(x0);
    float n1 = SELU_SCALE * SELU_ALPHA * expm1f(x1);
    out[r0 * N_CH + lane] = x0 > 0.f ? SELU_SCALE * x0 : n0;
    out[r1 * N_CH + lane] = x1 > 0.f ? SELU_SCALE * x1 : n1;
}

// ===========================================================================
// Fallback path (tiny ws): Round-0 atomic version (fp32 h)
// ===========================================================================
__global__ __launch_bounds__(256) void gemm_only_kernel(
    const float* __restrict__ feat, const float* __restrict__ W,
    const float* __restrict__ bias, float* __restrict__ h)
{
    int lane = threadIdx.x & 63;
    int wave = threadIdx.x >> 6;
    float Wc[D_FEAT];
    #pragma unroll
    for (int k = 0; k < D_FEAT; ++k) Wc[k] = W[k * N_CH + lane];
    float b = bias[lane];
    int row0 = (blockIdx.x * 4 + wave) * G_ROWS_PER_WAVE;
    for (int r = 0; r < G_ROWS_PER_WAVE; ++r) {
        int row = row0 + r;
        if (row >= N_NODES) return;
        int row_u = __builtin_amdgcn_readfirstlane(row);
        const float* frow = feat + (size_t)row_u * D_FEAT;
        float a0 = b, a1 = 0.f, a2 = 0.f, a3 = 0.f;
        #pragma unroll
        for (int k = 0; k < D_FEAT; k += 4) {
            a0 = fmaf(frow[k + 0], Wc[k + 0], a0);
            a1 = fmaf(frow[k + 1], Wc[k + 1], a1);
            a2 = fmaf(frow[k + 2], Wc[k + 2], a2);
            a3 = fmaf(frow[k + 3], Wc[k + 3], a3);
        }
        h[row * N_CH + lane] = (a0 + a1) + (a2 + a3);
    }
}

__global__ __launch_bounds__(256) void init_out_kernel(
    float* __restrict__ out, const float* __restrict__ skip)
{
    int idx = blockIdx.x * 256 + threadIdx.x;
    if (idx < N_NODES * N_CH) out[idx] = skip[idx & (N_CH - 1)];
}

__global__ __launch_bounds__(256) void edge_kernel(
    const float* __restrict__ vals, const int* __restrict__ rows,
    const int* __restrict__ cols, const float* __restrict__ h,
    float* __restrict__ out)
{
    int e = blockIdx.x * 4 + (threadIdx.x >> 6);
    int lane = threadIdx.x & 63;
    if (e >= N_EDGES) return;
    int row = rows[e];
    int col = cols[e];
    float v = vals[e];
    atomicAdd(&out[row * N_CH + lane], v * h[col * N_CH + lane]);
}

__global__ __launch_bounds__(256) void selu_kernel(float* __restrict__ out)
{
    int idx = blockIdx.x * 256 + threadIdx.x;
    if (idx >= N_NODES * N_CH) return;
    float x = out[idx];
    float neg = SELU_SCALE * SELU_ALPHA * expm1f(x);
    out[idx] = x > 0.f ? SELU_SCALE * x : neg;
}

// ===========================================================================
static inline size_t align256(size_t x) { return (x + 255) & ~(size_t)255; }

extern "C" void kernel_launch(void* const* d_in, const int* in_sizes, int n_in,
                              void* d_out, int out_size, void* d_ws, size_t ws_size,
                              hipStream_t stream)
{
    const float* features = (const float*)d_in[0];
    const float* W        = (const float*)d_in[1];
    const float* bias     = (const float*)d_in[2];
    const float* skip     = (const float*)d_in[3];
    const float* adj_vals = (const float*)d_in[4];
    const int*   adj_rows = (const int*)d_in[5];
    const int*   adj_cols = (const int*)d_in[6];
    float* out = (float*)d_out;

    // ---- workspace carve-up ----
    char* ws = (char*)d_ws;
    size_t off = 0;
    unsigned short* h_bf = (unsigned short*)(ws + off);
    off = align256(off + (size_t)N_NODES * N_CH * 2);               // 12.8 MB
    int* row_start = (int*)(ws + off);  off = align256(off + (size_t)(N_NODES + 1) * 4);
    int* deg       = (int*)(ws + off);  off = align256(off + (size_t)N_NODES * 4);
    int* partials  = (int*)(ws + off);  off = align256(off + 128 * 4);
    int* rank      = (int*)(ws + off);  off = align256(off + (size_t)N_EDGES * 4);
    unsigned long long* pack64 = (unsigned long long*)(ws + off);
    uint2* pack = (uint2*)(ws + off);
    size_t need = off + align256((size_t)N_EDGES * 8);

    if (ws_size >= need) {
        // ---- main path: bf16-h packed CSR ----
        zero_deg_kernel<<<(N_NODES + 255) / 256, 256, 0, stream>>>(deg);
        // degree+rank (8 edges/thread) || GEMM (both dependency-free heads)
        degree_rank_gemm_kernel<<<NB_SCAT8 + NB_GEMM, 256, 0, stream>>>(
            adj_rows, deg, rank, features, W, bias, h_bf);
        scan1_kernel<<<SCAN_NB, SCAN_TPB, 0, stream>>>(deg, row_start, partials);
        scan2_kernel<<<1, 128, 0, stream>>>(partials);
        scan3_kernel<<<SCAN_NB, SCAN_TPB, 0, stream>>>(row_start, partials);
        scatter_pack_kernel<<<NB_SCAT4, 256, 0, stream>>>(
            adj_rows, rank, adj_cols, adj_vals, row_start, pack64);
        aggregate_pack_kernel<<<(N_NODES / 2 + 3) / 4, 256, 0, stream>>>(
            row_start, pack, h_bf, skip, out);
    } else {
        // ---- fallback: atomic scatter (fp32 h in ws head) ----
        float* h = (float*)d_ws;
        gemm_only_kernel<<<NB_GEMM, 256, 0, stream>>>(features, W, bias, h);
        init_out_kernel<<<(N_NODES * N_CH + 255) / 256, 256, 0, stream>>>(out, skip);
        edge_kernel<<<(N_EDGES + 3) / 4, 256, 0, stream>>>(
            adj_vals, adj_rows, adj_cols, h, out);
        selu_kernel<<<(N_NODES * N_CH + 255) / 256, 256, 0, stream>>>(out);
    }
}